// Round 5
// baseline (1946.951 us; speedup 1.0000x reference)
//
#include <hip/hip_runtime.h>
#include <stdint.h>

// LSTM  B=128, S=256, I=1024, H=1024
// ONE fused persistent kernel (coop, 256 blocks x 512 thr, 1 block/CU):
//   blocks 128..255: x-GEMM producer  gx = Xc @ Wxp^T + bias  (full [32768][4096] bf16),
//     s-major tile order, sc1 stores, bump gxrdy[s] (32 tiles per s).
//   blocks 0..127:  recurrence consumer, block = (32 h x 4 gates) x (32 batch rows).
//     8 waves = (kh 0..3: K-quarter 256) x (wn 0..1: n-half 64). Wh slice pinned in
//     VGPRs (breg[32] = 128 VGPR). h streams directly global->VGPR from the 257-slot
//     ring; K-partials via pre[4][128][33]. Cross-block sync: PER-BLOCK FLAG WORDS
//     (no shared-counter RMW): block (mq,hgrp) stores s+1 into its own u32; wave 0
//     polls all 32 domain flags with one coalesced per-lane load (+__all), wave 1
//     polls gxrdy[s] in parallel. 3 barriers/step.
//
// Workspace layout (bytes)  [ws observed = 512 MiB via harness poison fills]:
//   Xc    bf16 [S*B][I]        67,108,864  @ 0           (row m = s*128 + b)
//   Whp   bf16 [4H][H]          8,388,608  @ 67,108,864  (n = gate*1024 + h; f,i,g,o)
//   Wxp   bf16 [4H][I]          8,388,608  @ 75,497,472
//   biasp f32  [4H]                16,384  @ 83,886,080
//   cws   f32  [128][1024]        524,288  @ 83,902,464
//   hring bf16 257*[32][128][32] 67,371,008 @ 84,426,752 (slot s = h entering step s)
//   gx    bf16 [32768][4096]  268,435,456  @ 151,797,760
// total 420,233,216

typedef unsigned short u16;
typedef unsigned int u32;
typedef __bf16 bf16x8 __attribute__((ext_vector_type(8)));
typedef float f32x4 __attribute__((ext_vector_type(4)));
typedef float f32x16 __attribute__((ext_vector_type(16)));

__device__ unsigned g_hflag[128];  // per-consumer-block publish flags: [mq][hgrp]
__device__ unsigned g_gxrdy[256];  // per-step gx tile counters (target 32)

__device__ __forceinline__ u16 f2bf(float f) {
  u32 u = __builtin_bit_cast(u32, f);
  u = (u + 0x7fffu + ((u >> 16) & 1u)) >> 16;
  return (u16)u;
}
__device__ __forceinline__ float bf2f(u16 s) {
  u32 u = ((u32)s) << 16;
  return __builtin_bit_cast(float, u);
}
__device__ __forceinline__ u32 pack2bf(float a, float b) {
  return (u32)f2bf(a) | ((u32)f2bf(b) << 16);
}

// async global -> LDS, 16B per lane. LDS dest must be wave-uniform base + lane*16.
__device__ __forceinline__ void gl2lds16(const void* gptr, void* lptr) {
  __builtin_amdgcn_global_load_lds(
      (__attribute__((address_space(1))) void*)(uintptr_t)gptr,
      (__attribute__((address_space(3))) void*)(uintptr_t)lptr, 16, 0, 0);
}

__device__ __forceinline__ float sigm(float x) { return 1.f / (1.f + __expf(-x)); }
__device__ __forceinline__ float tanh_f(float x) { return 2.f / (1.f + __expf(-2.f * x)) - 1.f; }

// ---------------- pack / convert kernels ----------------

// x [B][S][I] f32 -> Xc bf16 [S*B][I] with row m = s*128 + b
__global__ __launch_bounds__(256) void convert_x(const float* __restrict__ x, u16* __restrict__ Xc) {
  int t = blockIdx.x * 256 + threadIdx.x;  // 0..4194303
  int i8 = t & 127;
  int s = (t >> 7) & 255;
  int b = t >> 15;
  const float4* src = (const float4*)(x + (((b << 8) + s) << 10) + (i8 << 3));
  float4 a = src[0], c = src[1];
  uint4 o;
  o.x = pack2bf(a.x, a.y); o.y = pack2bf(a.z, a.w);
  o.z = pack2bf(c.x, c.y); o.w = pack2bf(c.z, c.w);
  *(uint4*)(Xc + (((s << 7) + b) << 10) + (i8 << 3)) = o;
}

__global__ __launch_bounds__(256) void pack_w(const float* __restrict__ Wf, const float* __restrict__ Wi,
                                              const float* __restrict__ Wc, const float* __restrict__ Wo,
                                              u16* __restrict__ Whp, u16* __restrict__ Wxp) {
  int t = blockIdx.x * 256 + threadIdx.x;  // 0..524287
  int k8 = t & 127, n = t >> 7;
  int g = n >> 10, h = n & 1023;
  const float* W = (g == 0) ? Wf : (g == 1) ? Wi : (g == 2) ? Wc : Wo;
  const float4* ph = (const float4*)(W + h * 2048 + (k8 << 3));
  float4 a = ph[0], b = ph[1];
  uint4 oh;
  oh.x = pack2bf(a.x, a.y); oh.y = pack2bf(a.z, a.w);
  oh.z = pack2bf(b.x, b.y); oh.w = pack2bf(b.z, b.w);
  *(uint4*)(Whp + n * 1024 + (k8 << 3)) = oh;
  const float4* px = (const float4*)(W + h * 2048 + 1024 + (k8 << 3));
  float4 c = px[0], d = px[1];
  uint4 ox;
  ox.x = pack2bf(c.x, c.y); ox.y = pack2bf(c.z, c.w);
  ox.z = pack2bf(d.x, d.y); ox.w = pack2bf(d.z, d.w);
  *(uint4*)(Wxp + n * 1024 + (k8 << 3)) = ox;
}

__global__ __launch_bounds__(256) void pack_b(const float* __restrict__ bf_, const float* __restrict__ bi,
                                              const float* __restrict__ bc, const float* __restrict__ bo,
                                              float* __restrict__ biasp) {
  if (blockIdx.x == 0 && threadIdx.x < 128) g_hflag[threadIdx.x] = 0;  // reset sync each replay
  if (blockIdx.x == 1) g_gxrdy[threadIdx.x] = 0;                       // 256 threads
  int n = blockIdx.x * 256 + threadIdx.x;  // 0..4095
  int g = n >> 10, h = n & 1023;
  const float* b = (g == 0) ? bf_ : (g == 1) ? bi : (g == 2) ? bc : bo;
  biasp[n] = b[h];
}

// ---------------- fused persistent kernel ----------------
__global__ __launch_bounds__(512, 2) void lstm_fused(
    const u16* __restrict__ Whp,   // [4096][1024]
    const u16* __restrict__ Wxp,   // [4096][1024]
    const u16* __restrict__ Xc,    // [32768][1024]
    const float* __restrict__ biasp,
    u16* __restrict__ gx,          // [32768][4096]
    u16* __restrict__ hring,       // 257 slots x [32][128][32] bf16
    float* __restrict__ cws,       // [128][1024]
    float* __restrict__ out) {     // [128][256][1024] f32
  __shared__ __align__(16) unsigned char smem[67584];
  const int tid = threadIdx.x;
  const int bid = blockIdx.x;

  if (bid >= 128) {
    // ================= GEMM producer role =================
    u16* lds_a = (u16*)smem;            // [2][128*64] (2 x 16KB)
    u16* lds_b = (u16*)(smem + 32768);  // [2][128*64]
    const int gid = bid - 128;
    const int lane = tid & 63, q = lane >> 4, cl = lane & 15;
    const int w = tid >> 6, wm = w & 1, wn = w >> 1;  // wm 0..1 (64m), wn 0..3 (32n)
    const int n0 = (gid & 31) * 128;                  // fixed n-panel per block (L2-resident B)

    for (int t = 0; t < 64; ++t) {
      const int s = (gid + (t << 7)) >> 5;  // s-major tile order
      const int m0 = s << 7;
      f32x4 acc[4][2] = {};

      auto stage = [&](int buf, int it) {
        const int k0 = it * 64;
#pragma unroll
        for (int itn = 0; itn < 2; ++itn) {  // A: 1024 granules of 16B
          int j = itn * 512 + tid;
          int row = j >> 3, c8s = (j & 7) ^ (row & 7);
          gl2lds16(Xc + (m0 + row) * 1024 + k0 + c8s * 8, lds_a + buf * 8192 + j * 8);
        }
#pragma unroll
        for (int itn = 0; itn < 2; ++itn) {  // B: 1024 granules
          int j = itn * 512 + tid;
          int row = j >> 3, c8s = (j & 7) ^ (row & 7);
          gl2lds16(Wxp + (n0 + row) * 1024 + k0 + c8s * 8, lds_b + buf * 8192 + j * 8);
        }
      };

      stage(0, 0);
      for (int it = 0; it < 16; ++it) {
        const int buf = it & 1;
        asm volatile("s_waitcnt vmcnt(0)" ::: "memory");
        __syncthreads();
        if (it < 15) stage(buf ^ 1, it + 1);
#pragma unroll
        for (int kk = 0; kk < 2; ++kk) {
          bf16x8 af[4], bfr[2];
#pragma unroll
          for (int mt = 0; mt < 4; ++mt) {
            int row = wm * 64 + mt * 16 + cl;
            int c8 = (kk * 4 + q) ^ (row & 7);
            af[mt] = *(const bf16x8*)&lds_a[buf * 8192 + row * 64 + c8 * 8];
          }
#pragma unroll
          for (int nt = 0; nt < 2; ++nt) {
            int row = wn * 32 + nt * 16 + cl;
            int c8 = (kk * 4 + q) ^ (row & 7);
            bfr[nt] = *(const bf16x8*)&lds_b[buf * 8192 + row * 64 + c8 * 8];
          }
#pragma unroll
          for (int mt = 0; mt < 4; ++mt)
#pragma unroll
            for (int nt = 0; nt < 2; ++nt)
              acc[mt][nt] = __builtin_amdgcn_mfma_f32_16x16x32_bf16(af[mt], bfr[nt], acc[mt][nt], 0, 0, 0);
        }
      }
      // epilogue: bias + bf16, sc1 (write-through) stores so consumers see LLC data
#pragma unroll
      for (int nt = 0; nt < 2; ++nt) {
        int n = n0 + wn * 32 + nt * 16 + cl;
        float bv = biasp[n];
#pragma unroll
        for (int mt = 0; mt < 4; ++mt)
#pragma unroll
          for (int r = 0; r < 4; ++r) {
            int m = m0 + wm * 64 + mt * 16 + q * 4 + r;
            __hip_atomic_store(&gx[m * 4096 + n], f2bf(acc[mt][nt][r] + bv),
                               __ATOMIC_RELAXED, __HIP_MEMORY_SCOPE_AGENT);
          }
      }
      asm volatile("s_waitcnt vmcnt(0)" ::: "memory");
      __syncthreads();
      if (tid == 0)
        __hip_atomic_fetch_add(&g_gxrdy[s], 1u, __ATOMIC_RELAXED, __HIP_MEMORY_SCOPE_AGENT);
    }
    return;
  }

  // ================= recurrence consumer role =================
  // hgrp = bid&31 -> h0 = 32*hgrp (n-set = 4 gates x 32 h = 128 Whp rows),
  // mq = bid>>5 -> m0 = 32*mq. Waves: kh = w>>1 (K-quarter 256), wn = w&1 (n-half 64).
  float* pre = (float*)smem;  // [4][128][33] f32 = 67584 B

  const int lane = tid & 63;
  const int w = tid >> 6;
  const int wn = w & 1;
  const int kh = w >> 1;
  const int l5 = lane >> 5, r31 = lane & 31;
  const int hgrp = bid & 31, mq = bid >> 5;
  const int h0 = hgrp * 32, m0 = mq * 32;

  // persistent Wh fragments: breg[ks*2+nb], 32 x bf16x8 = 128 VGPR
  bf16x8 breg[32];
  {
#pragma unroll
    for (int nb = 0; nb < 2; ++nb) {
      const int n_loc = wn * 64 + nb * 32 + r31;  // 0..127 = gate*32 + h-in
      const int ng = ((n_loc >> 5) << 10) + h0 + (n_loc & 31);
      const u16* wp = Whp + ng * 1024 + kh * 256 + l5 * 8;
#pragma unroll
      for (int ks = 0; ks < 16; ++ks) breg[ks * 2 + nb] = *(const bf16x8*)(wp + ks * 16);
    }
  }

  // per-lane A-fragment offset into an h slot (u16 units), invariant across steps:
  // elem (m,k) lives at (k>>5)*4096 + m*32 + (k&31); wave reads k-quarter kh.
  const int voff = kh * 32768 + (m0 + r31) * 32 + l5 * 8;

  // cell ownership: thread -> (m = tid>>4, h pair = (tid&15)*2); c-state in regs
  const int cm = tid >> 4, ch2 = (tid & 15) << 1;
  const int mg = m0 + cm;
  float2 cp = *(const float2*)&cws[mg * 1024 + h0 + ch2];
  float c0v = cp.x, c1v = cp.y;

  for (int s = 0; s < 256; ++s) {
    const u16* hb = hring + s * 131072 + voff;  // this wave's frag base for step s
    u16* hout = hring + (s + 1) * 131072;

    // parallel poll: wave 0 checks all 32 peer-block h flags (one coalesced per-lane
    // load per iteration, no shared-address RMW anywhere); wave 1 checks gx readiness.
    if (w == 0) {
      const unsigned tgt = (unsigned)s;
      unsigned* fp = &g_hflag[mq * 32 + (lane & 31)];
      while (!__all((int)(__hip_atomic_load(fp, __ATOMIC_RELAXED,
                                            __HIP_MEMORY_SCOPE_AGENT) >= tgt)))
        __builtin_amdgcn_s_sleep(1);
    } else if (w == 1) {
      while (__hip_atomic_load(&g_gxrdy[s], __ATOMIC_RELAXED, __HIP_MEMORY_SCOPE_AGENT) < 32u)
        __builtin_amdgcn_s_sleep(1);
    }
    __syncthreads();  // C: h[s] + gx[s] globally visible to everyone past here

    // gx prefetch (consumed in the cell update)
    const int gbase = (s * 128 + mg) * 4096 + h0 + ch2;
    const u32 gq0 = *(const u32*)(gx + gbase);
    const u32 gq1 = *(const u32*)(gx + gbase + 1024);
    const u32 gq2 = *(const u32*)(gx + gbase + 2048);
    const u32 gq3 = *(const u32*)(gx + gbase + 3072);

    // stream A-frags global->VGPR, 8 in flight; frag ks at (ks>>1)*4096 + (ks&1)*16
    f32x16 acc0 = {}, acc1 = {};
    bf16x8 av[8];
#pragma unroll
    for (int j = 0; j < 8; ++j)
      av[j] = *(const bf16x8*)(hb + ((j >> 1) << 12) + ((j & 1) << 4));
#pragma unroll
    for (int j = 0; j < 8; ++j) {
      const bf16x8 a = av[j];
      const int ks = 8 + j;
      av[j] = *(const bf16x8*)(hb + ((ks >> 1) << 12) + ((ks & 1) << 4));
      acc0 = __builtin_amdgcn_mfma_f32_32x32x16_bf16(a, breg[2 * j], acc0, 0, 0, 0);
      acc1 = __builtin_amdgcn_mfma_f32_32x32x16_bf16(a, breg[2 * j + 1], acc1, 0, 0, 0);
    }
#pragma unroll
    for (int j = 0; j < 8; ++j) {
      acc0 = __builtin_amdgcn_mfma_f32_32x32x16_bf16(av[j], breg[16 + 2 * j], acc0, 0, 0, 0);
      acc1 = __builtin_amdgcn_mfma_f32_32x32x16_bf16(av[j], breg[17 + 2 * j], acc1, 0, 0, 0);
    }

    // K-partial to LDS: C col = lane&31 (n), row m = (r&3)+8*(r>>2)+4*(lane>>5)
#pragma unroll
    for (int r = 0; r < 16; ++r) {
      const int m_l = (r & 3) + ((r >> 2) << 3) + (l5 << 2);
      pre[(kh * 128 + wn * 64 + r31) * 33 + m_l] = acc0[r];
      pre[(kh * 128 + wn * 64 + 32 + r31) * 33 + m_l] = acc1[r];
    }
    __syncthreads();  // A: all K-partials in LDS

    // fused cell update: 2 cells per thread (h pair), sum 4 K-partials + gates_x
    float p0[4], p1[4];
#pragma unroll
    for (int gi = 0; gi < 4; ++gi) {
      const int n0l = gi * 32 + ch2;
      p0[gi] = pre[n0l * 33 + cm] + pre[(128 + n0l) * 33 + cm] +
               pre[(256 + n0l) * 33 + cm] + pre[(384 + n0l) * 33 + cm];
      p1[gi] = pre[(n0l + 1) * 33 + cm] + pre[(128 + n0l + 1) * 33 + cm] +
               pre[(256 + n0l + 1) * 33 + cm] + pre[(384 + n0l + 1) * 33 + cm];
    }
    p0[0] += bf2f((u16)(gq0 & 0xffff)); p1[0] += bf2f((u16)(gq0 >> 16));
    p0[1] += bf2f((u16)(gq1 & 0xffff)); p1[1] += bf2f((u16)(gq1 >> 16));
    p0[2] += bf2f((u16)(gq2 & 0xffff)); p1[2] += bf2f((u16)(gq2 >> 16));
    p0[3] += bf2f((u16)(gq3 & 0xffff)); p1[3] += bf2f((u16)(gq3 >> 16));
    const float fg0 = sigm(p0[0]), ig0 = sigm(p0[1]), gg0 = tanh_f(p0[2]), og0 = sigm(p0[3]);
    const float fg1 = sigm(p1[0]), ig1 = sigm(p1[1]), gg1 = tanh_f(p1[2]), og1 = sigm(p1[3]);
    c0v = c0v * fg0 + ig0 * gg0;
    c1v = c1v * fg1 + ig1 * gg1;
    const float hn0 = tanh_f(c0v) * og0;
    const float hn1 = tanh_f(c1v) * og1;

    // coherent h store (one u32 = 2 bf16); must be LLC-visible before the flag
    __hip_atomic_store((u32*)(hout + hgrp * 4096 + mg * 32 + ch2), pack2bf(hn0, hn1),
                       __ATOMIC_RELAXED, __HIP_MEMORY_SCOPE_AGENT);
    asm volatile("s_waitcnt vmcnt(0)" ::: "memory");
    __syncthreads();  // B: whole block's h published (every wave vmcnt(0)'d its own)
    if (tid == 0)
      __hip_atomic_store(&g_hflag[mq * 32 + hgrp], (unsigned)(s + 1),
                         __ATOMIC_RELAXED, __HIP_MEMORY_SCOPE_AGENT);

    // out store AFTER the flag: off the cross-block critical path
    *(float2*)&out[(mg * 256 + s) * 1024 + h0 + ch2] = make_float2(hn0, hn1);
  }
  *(float2*)&cws[mg * 1024 + h0 + ch2] = make_float2(c0v, c1v);
}

// ---------------- launch ----------------

extern "C" void kernel_launch(void* const* d_in, const int* in_sizes, int n_in,
                              void* d_out, int out_size, void* d_ws, size_t ws_size,
                              hipStream_t stream) {
  const float* x   = (const float*)d_in[0];
  const float* Wf  = (const float*)d_in[1];
  const float* bf_ = (const float*)d_in[2];
  const float* Wi  = (const float*)d_in[3];
  const float* bi  = (const float*)d_in[4];
  const float* Wc  = (const float*)d_in[5];
  const float* bc  = (const float*)d_in[6];
  const float* Wo  = (const float*)d_in[7];
  const float* bo  = (const float*)d_in[8];
  float* out = (float*)d_out;
  char* ws = (char*)d_ws;

  const size_t NEEDED = 420233216;
  if (ws_size < NEEDED) return;  // fail cleanly (wrong output) instead of faulting

  u16*  Xc    = (u16*)(ws);
  u16*  Whp   = (u16*)(ws + 67108864);
  u16*  Wxp   = (u16*)(ws + 75497472);
  float* biasp = (float*)(ws + 83886080);
  float* cws  = (float*)(ws + 83902464);
  u16*  hring = (u16*)(ws + 84426752);    // 257 x 262144 B
  u16*  gx    = (u16*)(ws + 151797760);   // 256 MB

  hipMemsetAsync(ws + 83902464, 0, 524288, stream);  // cws = 0
  hipMemsetAsync(ws + 84426752, 0, 262144, stream);  // hring slot 0 = 0
  convert_x<<<16384, 256, 0, stream>>>(x, Xc);
  pack_w<<<2048, 256, 0, stream>>>(Wf, Wi, Wc, Wo, Whp, Wxp);
  pack_b<<<16, 256, 0, stream>>>(bf_, bi, bc, bo, biasp);  // also zeroes g_hflag/g_gxrdy

  void* args[8];
  args[0] = (void*)&Whp;
  args[1] = (void*)&Wxp;
  args[2] = (void*)&Xc;
  args[3] = (void*)&biasp;
  args[4] = (void*)&gx;
  args[5] = (void*)&hring;
  args[6] = (void*)&cws;
  args[7] = (void*)&out;
  if (hipLaunchCooperativeKernel((const void*)lstm_fused, dim3(256), dim3(512),
                                 args, 0, stream) != hipSuccess) {
    // fallback: plain launch. 256 blocks, <=1/CU by resources => co-resident;
    // flag-based sync does not require more than co-residency.
    lstm_fused<<<dim3(256), dim3(512), 0, stream>>>(Whp, Wxp, Xc, biasp, gx, hring, cws, out);
  }
}

// Round 6
// 1572.390 us; speedup vs baseline: 1.2382x; 1.2382x over previous
//
#include <hip/hip_runtime.h>
#include <stdint.h>

// LSTM  B=128, S=256, I=1024, H=1024
// ONE fused persistent kernel (coop, 256 blocks x 512 thr, 1 block/CU):
//   blocks 128..255: x-GEMM producer  gx = Xc @ Wxp^T + bias  (full [32768][4096] bf16),
//     s-major tile order, sc1 stores, bump gxrdy[s] (32 tiles per s).
//   blocks 0..127:  recurrence consumer, block = (32 h x 4 gates) x (32 batch rows).
//     8 waves = (kh 0..3: K-quarter 256) x (wn 0..1: n-half 64). Wh slice TRULY pinned
//     in VGPRs: loaded as u32x4 and passed through an opaque asm identity so the
//     compiler cannot rematerialize the loads (round-5 post-mortem: VGPR_Count=112
//     proved breg[32]=128 VGPR was being re-loaded from L2 every step). h streams
//     directly global->VGPR from the 257-slot ring; K-partials via pre[4][128][33].
//     Sync = round-4 mechanism (measured best): per-mq counter, tid0 serial poll.
//
// Workspace layout (bytes)  [ws observed = 512 MiB via harness poison fills]:
//   Xc    bf16 [S*B][I]        67,108,864  @ 0           (row m = s*128 + b)
//   Whp   bf16 [4H][H]          8,388,608  @ 67,108,864  (n = gate*1024 + h; f,i,g,o)
//   Wxp   bf16 [4H][I]          8,388,608  @ 75,497,472
//   biasp f32  [4H]                16,384  @ 83,886,080
//   cws   f32  [128][1024]        524,288  @ 83,902,464
//   hring bf16 257*[32][128][32] 67,371,008 @ 84,426,752 (slot s = h entering step s)
//   gx    bf16 [32768][4096]  268,435,456  @ 151,797,760
// total 420,233,216

typedef unsigned short u16;
typedef unsigned int u32;
typedef __bf16 bf16x8 __attribute__((ext_vector_type(8)));
typedef float f32x4 __attribute__((ext_vector_type(4)));
typedef float f32x16 __attribute__((ext_vector_type(16)));
typedef unsigned int u32x4 __attribute__((ext_vector_type(4)));

__device__ unsigned g_bars[128];   // per-mq h counters at g_bars[mq*32]
__device__ unsigned g_gxrdy[256];  // per-step gx tile counters (target 32)

__device__ __forceinline__ u16 f2bf(float f) {
  u32 u = __builtin_bit_cast(u32, f);
  u = (u + 0x7fffu + ((u >> 16) & 1u)) >> 16;
  return (u16)u;
}
__device__ __forceinline__ float bf2f(u16 s) {
  u32 u = ((u32)s) << 16;
  return __builtin_bit_cast(float, u);
}
__device__ __forceinline__ u32 pack2bf(float a, float b) {
  return (u32)f2bf(a) | ((u32)f2bf(b) << 16);
}

// async global -> LDS, 16B per lane. LDS dest must be wave-uniform base + lane*16.
__device__ __forceinline__ void gl2lds16(const void* gptr, void* lptr) {
  __builtin_amdgcn_global_load_lds(
      (__attribute__((address_space(1))) void*)(uintptr_t)gptr,
      (__attribute__((address_space(3))) void*)(uintptr_t)lptr, 16, 0, 0);
}

__device__ __forceinline__ float sigm(float x) { return 1.f / (1.f + __expf(-x)); }
__device__ __forceinline__ float tanh_f(float x) { return 2.f / (1.f + __expf(-2.f * x)) - 1.f; }

// ---------------- pack / convert kernels ----------------

// x [B][S][I] f32 -> Xc bf16 [S*B][I] with row m = s*128 + b
__global__ __launch_bounds__(256) void convert_x(const float* __restrict__ x, u16* __restrict__ Xc) {
  int t = blockIdx.x * 256 + threadIdx.x;  // 0..4194303
  int i8 = t & 127;
  int s = (t >> 7) & 255;
  int b = t >> 15;
  const float4* src = (const float4*)(x + (((b << 8) + s) << 10) + (i8 << 3));
  float4 a = src[0], c = src[1];
  uint4 o;
  o.x = pack2bf(a.x, a.y); o.y = pack2bf(a.z, a.w);
  o.z = pack2bf(c.x, c.y); o.w = pack2bf(c.z, c.w);
  *(uint4*)(Xc + (((s << 7) + b) << 10) + (i8 << 3)) = o;
}

__global__ __launch_bounds__(256) void pack_w(const float* __restrict__ Wf, const float* __restrict__ Wi,
                                              const float* __restrict__ Wc, const float* __restrict__ Wo,
                                              u16* __restrict__ Whp, u16* __restrict__ Wxp) {
  int t = blockIdx.x * 256 + threadIdx.x;  // 0..524287
  int k8 = t & 127, n = t >> 7;
  int g = n >> 10, h = n & 1023;
  const float* W = (g == 0) ? Wf : (g == 1) ? Wi : (g == 2) ? Wc : Wo;
  const float4* ph = (const float4*)(W + h * 2048 + (k8 << 3));
  float4 a = ph[0], b = ph[1];
  uint4 oh;
  oh.x = pack2bf(a.x, a.y); oh.y = pack2bf(a.z, a.w);
  oh.z = pack2bf(b.x, b.y); oh.w = pack2bf(b.z, b.w);
  *(uint4*)(Whp + n * 1024 + (k8 << 3)) = oh;
  const float4* px = (const float4*)(W + h * 2048 + 1024 + (k8 << 3));
  float4 c = px[0], d = px[1];
  uint4 ox;
  ox.x = pack2bf(c.x, c.y); ox.y = pack2bf(c.z, c.w);
  ox.z = pack2bf(d.x, d.y); ox.w = pack2bf(d.z, d.w);
  *(uint4*)(Wxp + n * 1024 + (k8 << 3)) = ox;
}

__global__ __launch_bounds__(256) void pack_b(const float* __restrict__ bf_, const float* __restrict__ bi,
                                              const float* __restrict__ bc, const float* __restrict__ bo,
                                              float* __restrict__ biasp) {
  if (blockIdx.x == 0 && threadIdx.x < 128) g_bars[threadIdx.x] = 0;   // reset sync each replay
  if (blockIdx.x == 1) g_gxrdy[threadIdx.x] = 0;                       // 256 threads
  int n = blockIdx.x * 256 + threadIdx.x;  // 0..4095
  int g = n >> 10, h = n & 1023;
  const float* b = (g == 0) ? bf_ : (g == 1) ? bi : (g == 2) ? bc : bo;
  biasp[n] = b[h];
}

// ---------------- fused persistent kernel ----------------
__global__ __launch_bounds__(512, 2) void lstm_fused(
    const u16* __restrict__ Whp,   // [4096][1024]
    const u16* __restrict__ Wxp,   // [4096][1024]
    const u16* __restrict__ Xc,    // [32768][1024]
    const float* __restrict__ biasp,
    u16* __restrict__ gx,          // [32768][4096]
    u16* __restrict__ hring,       // 257 slots x [32][128][32] bf16
    float* __restrict__ cws,       // [128][1024]
    float* __restrict__ out) {     // [128][256][1024] f32
  __shared__ __align__(16) unsigned char smem[67584];
  const int tid = threadIdx.x;
  const int bid = blockIdx.x;

  if (bid >= 128) {
    // ================= GEMM producer role =================
    u16* lds_a = (u16*)smem;            // [2][128*64] (2 x 16KB)
    u16* lds_b = (u16*)(smem + 32768);  // [2][128*64]
    const int gid = bid - 128;
    const int lane = tid & 63, q = lane >> 4, cl = lane & 15;
    const int w = tid >> 6, wm = w & 1, wn = w >> 1;  // wm 0..1 (64m), wn 0..3 (32n)
    const int n0 = (gid & 31) * 128;                  // fixed n-panel per block (L2-resident B)

    for (int t = 0; t < 64; ++t) {
      const int s = (gid + (t << 7)) >> 5;  // s-major tile order
      const int m0 = s << 7;
      f32x4 acc[4][2] = {};

      auto stage = [&](int buf, int it) {
        const int k0 = it * 64;
#pragma unroll
        for (int itn = 0; itn < 2; ++itn) {  // A: 1024 granules of 16B
          int j = itn * 512 + tid;
          int row = j >> 3, c8s = (j & 7) ^ (row & 7);
          gl2lds16(Xc + (m0 + row) * 1024 + k0 + c8s * 8, lds_a + buf * 8192 + j * 8);
        }
#pragma unroll
        for (int itn = 0; itn < 2; ++itn) {  // B: 1024 granules
          int j = itn * 512 + tid;
          int row = j >> 3, c8s = (j & 7) ^ (row & 7);
          gl2lds16(Wxp + (n0 + row) * 1024 + k0 + c8s * 8, lds_b + buf * 8192 + j * 8);
        }
      };

      stage(0, 0);
      for (int it = 0; it < 16; ++it) {
        const int buf = it & 1;
        asm volatile("s_waitcnt vmcnt(0)" ::: "memory");
        __syncthreads();
        if (it < 15) stage(buf ^ 1, it + 1);
#pragma unroll
        for (int kk = 0; kk < 2; ++kk) {
          bf16x8 af[4], bfr[2];
#pragma unroll
          for (int mt = 0; mt < 4; ++mt) {
            int row = wm * 64 + mt * 16 + cl;
            int c8 = (kk * 4 + q) ^ (row & 7);
            af[mt] = *(const bf16x8*)&lds_a[buf * 8192 + row * 64 + c8 * 8];
          }
#pragma unroll
          for (int nt = 0; nt < 2; ++nt) {
            int row = wn * 32 + nt * 16 + cl;
            int c8 = (kk * 4 + q) ^ (row & 7);
            bfr[nt] = *(const bf16x8*)&lds_b[buf * 8192 + row * 64 + c8 * 8];
          }
#pragma unroll
          for (int mt = 0; mt < 4; ++mt)
#pragma unroll
            for (int nt = 0; nt < 2; ++nt)
              acc[mt][nt] = __builtin_amdgcn_mfma_f32_16x16x32_bf16(af[mt], bfr[nt], acc[mt][nt], 0, 0, 0);
        }
      }
      // epilogue: bias + bf16, sc1 (write-through) stores so consumers see LLC data
#pragma unroll
      for (int nt = 0; nt < 2; ++nt) {
        int n = n0 + wn * 32 + nt * 16 + cl;
        float bv = biasp[n];
#pragma unroll
        for (int mt = 0; mt < 4; ++mt)
#pragma unroll
          for (int r = 0; r < 4; ++r) {
            int m = m0 + wm * 64 + mt * 16 + q * 4 + r;
            __hip_atomic_store(&gx[m * 4096 + n], f2bf(acc[mt][nt][r] + bv),
                               __ATOMIC_RELAXED, __HIP_MEMORY_SCOPE_AGENT);
          }
      }
      asm volatile("s_waitcnt vmcnt(0)" ::: "memory");
      __syncthreads();
      if (tid == 0)
        __hip_atomic_fetch_add(&g_gxrdy[s], 1u, __ATOMIC_RELAXED, __HIP_MEMORY_SCOPE_AGENT);
    }
    return;
  }

  // ================= recurrence consumer role =================
  // hgrp = bid&31 -> h0 = 32*hgrp (n-set = 4 gates x 32 h = 128 Whp rows),
  // mq = bid>>5 -> m0 = 32*mq. Waves: kh = w>>1 (K-quarter 256), wn = w&1 (n-half 64).
  float* pre = (float*)smem;  // [4][128][33] f32 = 67584 B

  const int lane = tid & 63;
  const int w = tid >> 6;
  const int wn = w & 1;
  const int kh = w >> 1;
  const int l5 = lane >> 5, r31 = lane & 31;
  const int hgrp = bid & 31, mq = bid >> 5;
  const int h0 = hgrp * 32, m0 = mq * 32;
  unsigned* ctr = &g_bars[mq * 32];

  // persistent Wh fragments, FORCE-pinned in VGPRs: 32 x u32x4 = 128 VGPR.
  // The opaque asm identity makes each value an asm result -> compiler cannot
  // rematerialize the global load inside the step loop (round-5 bug).
  u32x4 bw[32];
  {
#pragma unroll
    for (int nb = 0; nb < 2; ++nb) {
      const int n_loc = wn * 64 + nb * 32 + r31;  // 0..127 = gate*32 + h-in
      const int ng = ((n_loc >> 5) << 10) + h0 + (n_loc & 31);
      const u16* wp = Whp + ng * 1024 + kh * 256 + l5 * 8;
#pragma unroll
      for (int ks = 0; ks < 16; ++ks) bw[ks * 2 + nb] = *(const u32x4*)(wp + ks * 16);
    }
#pragma unroll
    for (int i = 0; i < 32; ++i) {
      u32 a0 = bw[i][0], a1 = bw[i][1], a2 = bw[i][2], a3 = bw[i][3];
      asm volatile("" : "+v"(a0), "+v"(a1), "+v"(a2), "+v"(a3));
      bw[i][0] = a0; bw[i][1] = a1; bw[i][2] = a2; bw[i][3] = a3;
    }
  }

  // per-lane A-fragment offset into an h slot (u16 units), invariant across steps:
  // elem (m,k) lives at (k>>5)*4096 + m*32 + (k&31); wave reads k-quarter kh.
  const int voff = kh * 32768 + (m0 + r31) * 32 + l5 * 8;

  // cell ownership: thread -> (m = tid>>4, h pair = (tid&15)*2); c-state in regs
  const int cm = tid >> 4, ch2 = (tid & 15) << 1;
  const int mg = m0 + cm;
  float2 cp = *(const float2*)&cws[mg * 1024 + h0 + ch2];
  float c0v = cp.x, c1v = cp.y;

  for (int s = 0; s < 256; ++s) {
    const u16* hb = hring + s * 131072 + voff;  // this wave's frag base for step s
    u16* hout = hring + (s + 1) * 131072;

    if (tid == 0) {
      while (__hip_atomic_load(&g_gxrdy[s], __ATOMIC_RELAXED, __HIP_MEMORY_SCOPE_AGENT) < 32u)
        __builtin_amdgcn_s_sleep(1);
      const unsigned tgt = 32u * (unsigned)s;
      while (__hip_atomic_load(ctr, __ATOMIC_RELAXED, __HIP_MEMORY_SCOPE_AGENT) < tgt)
        __builtin_amdgcn_s_sleep(1);
    }
    __syncthreads();  // C: h[s] + gx[s] globally visible to everyone past here

    // gx prefetch (consumed in the cell update)
    const int gbase = (s * 128 + mg) * 4096 + h0 + ch2;
    const u32 gq0 = *(const u32*)(gx + gbase);
    const u32 gq1 = *(const u32*)(gx + gbase + 1024);
    const u32 gq2 = *(const u32*)(gx + gbase + 2048);
    const u32 gq3 = *(const u32*)(gx + gbase + 3072);

    // stream A-frags global->VGPR, 8 in flight; frag ks at (ks>>1)*4096 + (ks&1)*16
    f32x16 acc0 = {}, acc1 = {};
    bf16x8 av[8];
#pragma unroll
    for (int j = 0; j < 8; ++j)
      av[j] = *(const bf16x8*)(hb + ((j >> 1) << 12) + ((j & 1) << 4));
#pragma unroll
    for (int j = 0; j < 8; ++j) {
      const bf16x8 a = av[j];
      const int ks = 8 + j;
      av[j] = *(const bf16x8*)(hb + ((ks >> 1) << 12) + ((ks & 1) << 4));
      acc0 = __builtin_amdgcn_mfma_f32_32x32x16_bf16(a, __builtin_bit_cast(bf16x8, bw[2 * j]), acc0, 0, 0, 0);
      acc1 = __builtin_amdgcn_mfma_f32_32x32x16_bf16(a, __builtin_bit_cast(bf16x8, bw[2 * j + 1]), acc1, 0, 0, 0);
    }
#pragma unroll
    for (int j = 0; j < 8; ++j) {
      acc0 = __builtin_amdgcn_mfma_f32_32x32x16_bf16(av[j], __builtin_bit_cast(bf16x8, bw[16 + 2 * j]), acc0, 0, 0, 0);
      acc1 = __builtin_amdgcn_mfma_f32_32x32x16_bf16(av[j], __builtin_bit_cast(bf16x8, bw[17 + 2 * j]), acc1, 0, 0, 0);
    }

    // K-partial to LDS: C col = lane&31 (n), row m = (r&3)+8*(r>>2)+4*(lane>>5)
#pragma unroll
    for (int r = 0; r < 16; ++r) {
      const int m_l = (r & 3) + ((r >> 2) << 3) + (l5 << 2);
      pre[(kh * 128 + wn * 64 + r31) * 33 + m_l] = acc0[r];
      pre[(kh * 128 + wn * 64 + 32 + r31) * 33 + m_l] = acc1[r];
    }
    __syncthreads();  // A: all K-partials in LDS

    // fused cell update: 2 cells per thread (h pair), sum 4 K-partials + gates_x
    float p0[4], p1[4];
#pragma unroll
    for (int gi = 0; gi < 4; ++gi) {
      const int n0l = gi * 32 + ch2;
      p0[gi] = pre[n0l * 33 + cm] + pre[(128 + n0l) * 33 + cm] +
               pre[(256 + n0l) * 33 + cm] + pre[(384 + n0l) * 33 + cm];
      p1[gi] = pre[(n0l + 1) * 33 + cm] + pre[(128 + n0l + 1) * 33 + cm] +
               pre[(256 + n0l + 1) * 33 + cm] + pre[(384 + n0l + 1) * 33 + cm];
    }
    p0[0] += bf2f((u16)(gq0 & 0xffff)); p1[0] += bf2f((u16)(gq0 >> 16));
    p0[1] += bf2f((u16)(gq1 & 0xffff)); p1[1] += bf2f((u16)(gq1 >> 16));
    p0[2] += bf2f((u16)(gq2 & 0xffff)); p1[2] += bf2f((u16)(gq2 >> 16));
    p0[3] += bf2f((u16)(gq3 & 0xffff)); p1[3] += bf2f((u16)(gq3 >> 16));
    const float fg0 = sigm(p0[0]), ig0 = sigm(p0[1]), gg0 = tanh_f(p0[2]), og0 = sigm(p0[3]);
    const float fg1 = sigm(p1[0]), ig1 = sigm(p1[1]), gg1 = tanh_f(p1[2]), og1 = sigm(p1[3]);
    c0v = c0v * fg0 + ig0 * gg0;
    c1v = c1v * fg1 + ig1 * gg1;
    const float hn0 = tanh_f(c0v) * og0;
    const float hn1 = tanh_f(c1v) * og1;

    // coherent h store (one u32 = 2 bf16); must be LLC-visible before the bump
    __hip_atomic_store((u32*)(hout + hgrp * 4096 + mg * 32 + ch2), pack2bf(hn0, hn1),
                       __ATOMIC_RELAXED, __HIP_MEMORY_SCOPE_AGENT);
    asm volatile("s_waitcnt vmcnt(0)" ::: "memory");
    __syncthreads();  // B: whole block's h published (every wave vmcnt(0)'d its own)
    if (tid == 0)
      __hip_atomic_fetch_add(ctr, 1u, __ATOMIC_RELAXED, __HIP_MEMORY_SCOPE_AGENT);

    // out store AFTER the bump: off the cross-block critical path
    *(float2*)&out[(mg * 256 + s) * 1024 + h0 + ch2] = make_float2(hn0, hn1);
  }
  *(float2*)&cws[mg * 1024 + h0 + ch2] = make_float2(c0v, c1v);
}

// ---------------- launch ----------------

extern "C" void kernel_launch(void* const* d_in, const int* in_sizes, int n_in,
                              void* d_out, int out_size, void* d_ws, size_t ws_size,
                              hipStream_t stream) {
  const float* x   = (const float*)d_in[0];
  const float* Wf  = (const float*)d_in[1];
  const float* bf_ = (const float*)d_in[2];
  const float* Wi  = (const float*)d_in[3];
  const float* bi  = (const float*)d_in[4];
  const float* Wc  = (const float*)d_in[5];
  const float* bc  = (const float*)d_in[6];
  const float* Wo  = (const float*)d_in[7];
  const float* bo  = (const float*)d_in[8];
  float* out = (float*)d_out;
  char* ws = (char*)d_ws;

  const size_t NEEDED = 420233216;
  if (ws_size < NEEDED) return;  // fail cleanly (wrong output) instead of faulting

  u16*  Xc    = (u16*)(ws);
  u16*  Whp   = (u16*)(ws + 67108864);
  u16*  Wxp   = (u16*)(ws + 75497472);
  float* biasp = (float*)(ws + 83886080);
  float* cws  = (float*)(ws + 83902464);
  u16*  hring = (u16*)(ws + 84426752);    // 257 x 262144 B
  u16*  gx    = (u16*)(ws + 151797760);   // 256 MB

  hipMemsetAsync(ws + 83902464, 0, 524288, stream);  // cws = 0
  hipMemsetAsync(ws + 84426752, 0, 262144, stream);  // hring slot 0 = 0
  convert_x<<<16384, 256, 0, stream>>>(x, Xc);
  pack_w<<<2048, 256, 0, stream>>>(Wf, Wi, Wc, Wo, Whp, Wxp);
  pack_b<<<16, 256, 0, stream>>>(bf_, bi, bc, bo, biasp);  // also zeroes g_bars/g_gxrdy

  void* args[8];
  args[0] = (void*)&Whp;
  args[1] = (void*)&Wxp;
  args[2] = (void*)&Xc;
  args[3] = (void*)&biasp;
  args[4] = (void*)&gx;
  args[5] = (void*)&hring;
  args[6] = (void*)&cws;
  args[7] = (void*)&out;
  if (hipLaunchCooperativeKernel((const void*)lstm_fused, dim3(256), dim3(512),
                                 args, 0, stream) != hipSuccess) {
    // fallback: plain launch. 256 blocks, <=1/CU by resources => co-resident;
    // flag-based sync does not require more than co-residency.
    lstm_fused<<<dim3(256), dim3(512), 0, stream>>>(Whp, Wxp, Xc, biasp, gx, hring, cws, out);
  }
}